// Round 4
// baseline (97.807 us; speedup 1.0000x reference)
//
#include <hip/hip_runtime.h>
#include <math.h>

#define NH 32     // total modes (N/2)
#define NHALF 16  // modes per thread (lane-split)

typedef float v2f __attribute__((ext_vector_type(2)));

// Reduce x mod 2*pi to [-pi, pi] with 2-term float Cody-Waite.
// PI2_HI = 6.28125 (7-bit mantissa) -> k*PI2_HI exact for k < 2^16.
// Total error ~3e-7 rad for |x| <= ~2.2e4.
__device__ __forceinline__ float reduce2pi(float x) {
    const float INV2PI = 0.15915494309189535f;
    const float PI2_HI = 6.28125f;
    const float PI2_LO = 1.9353071795864769e-3f;
    float k = rintf(x * INV2PI);
    float r = fmaf(-k, PI2_HI, x);
    r = fmaf(-k, PI2_LO, r);
    return r;
}

// One block per h, 256 threads (4 waves), ALL 1024 blocks resident (4/CU).
// Lane-split: lanes 0-31 handle modes 0-15, lanes 32-63 modes 16-31.
// Each thread carries TWO l-positions: l0 + j*128 and L/2 + l0 + j*128
// (same step multiplier w = exp(dtA*128); second state seeded by one
// complex mul with B = exp(dtA*L/2)). Per step, two shfl_xor(32) reductions
// give both totals to every lane; lanes<32 store the first l, lanes>=32 the
// second -> unpredicated, fully coalesced stores.
__global__ __launch_bounds__(256, 4) void s4d_kernel(
    const float* __restrict__ log_dt,
    const float* __restrict__ Cv,          // (H, 32, 2)
    const float* __restrict__ log_A_real,  // (H, 32)
    const float* __restrict__ A_imag,      // (H, 32)
    float* __restrict__ Kout,              // (H, L)
    int L)
{
    const int h   = blockIdx.x;
    const int tid = threadIdx.x;
    const int Lh  = L >> 1;                // 2048 = 2^11 (exact fp32 scaling)

    __shared__ float s_ce[NH][2];  // C_eff (x2 folded)
    __shared__ float s_w [NH][2];  // w = exp(dtA*128)
    __shared__ float s_B [NH][2];  // B = exp(dtA*L/2)
    __shared__ float s_da[NH][2];  // (dar, dai)

    // ---- Phase A: per-(h,n) uniforms; 32 threads; HW trans only ----
    if (tid < NH) {
        const int n = tid;
        const float dt  = __expf(log_dt[h]);
        const float Ar  = -__expf(log_A_real[h * NH + n]);
        const float Ai  = A_imag[h * NH + n];
        const float dar = Ar * dt;
        const float dai = Ai * dt;

        // C_eff = 2 * C * (exp(dtA) - 1) / A
        float er = __expf(dar);
        float sn, cs;
        __sincosf(dai, &sn, &cs);          // |dai| <= ~9.8
        float edr = fmaf(er, cs, -1.0f);
        float edi = er * sn;
        float inv = 1.0f / fmaf(Ar, Ar, Ai * Ai);
        float fr  = (edr * Ar + edi * Ai) * inv;
        float fi  = (edi * Ar - edr * Ai) * inv;
        float cr  = Cv[(h * NH + n) * 2 + 0];
        float ci  = Cv[(h * NH + n) * 2 + 1];
        s_ce[n][0] = 2.0f * (cr * fr - ci * fi);
        s_ce[n][1] = 2.0f * (cr * fi + ci * fr);

        // w = exp(dtA*128); dai*128 exact (power of 2)
        float ew  = __expf(dar * 128.0f);
        float thw = reduce2pi(dai * 128.0f);
        float sw, cw;
        __sincosf(thw, &sw, &cw);
        s_w[n][0] = ew * cw;
        s_w[n][1] = ew * sw;

        // B = exp(dtA*Lh); Lh power of 2 -> dai*Lh exact; may underflow (mode dead)
        float Bf  = (float)Lh;
        float eB  = __expf(dar * Bf);
        float thB = reduce2pi(dai * Bf);
        float sB, cB;
        __sincosf(thB, &sB, &cB);
        s_B[n][0] = eB * cB;
        s_B[n][1] = eB * sB;

        s_da[n][0] = dar;
        s_da[n][1] = dai;
    }
    __syncthreads();

    // ---- Phase B: per-thread state init ----
    const int lane = tid & 63;
    const int half = lane >> 5;                       // 0: modes 0-15, 1: 16-31
    const int l0   = (tid >> 6) * 32 + (lane & 31);   // 0..127
    const float l0f = (float)l0;

    v2f y1[NHALF], y2[NHALF], w[NHALF];
    #pragma unroll
    for (int m = 0; m < NHALF; ++m) {
        const int n = half * NHALF + m;
        float dar = s_da[n][0], dai = s_da[n][1];
        float e0 = __expf(dar * l0f);
        float sn, cs;
        __sincosf(dai * l0f, &sn, &cs);               // |ang| <= ~1240 rad
        float zr = e0 * cs, zi = e0 * sn;
        float cr = s_ce[n][0], ci = s_ce[n][1];
        float ar = cr * zr - ci * zi;
        float ai = cr * zi + ci * zr;
        y1[m][0] = ar;
        y1[m][1] = ai;
        // y2 = y1 * B  (seed the second l-position, spaced Lh)
        float Br = s_B[n][0], Bi = s_B[n][1];
        y2[m][0] = ar * Br - ai * Bi;
        y2[m][1] = ar * Bi + ai * Br;
        w[m][0] = s_w[n][0];
        w[m][1] = s_w[n][1];
    }

    // ---- Main loop: 16 steps; each step produces 256 outputs per block ----
    float* outp = Kout + (size_t)h * (size_t)L + (half ? Lh : 0) + l0;
    const int steps = L >> 8;                         // L/256 = 16
    #pragma unroll 2
    for (int j = 0; j < steps; ++j) {
        v2f a1a = {0.f, 0.f}, a1b = {0.f, 0.f};
        v2f a2a = {0.f, 0.f}, a2b = {0.f, 0.f};
        #pragma unroll
        for (int m = 0; m < NHALF; m += 2) {
            a1a += y1[m];  a1b += y1[m + 1];
            a2a += y2[m];  a2b += y2[m + 1];
            #pragma unroll
            for (int q = 0; q < 2; ++q) {
                v2f t1, t2;
                // complex y *= w in 2 VOP3P ops each:
                // t  = (yr*wr, yr*wi);  y' = (-yi*wi + t.lo, yi*wr + t.hi)
                asm("v_pk_mul_f32 %0, %1, %2 op_sel:[0,0] op_sel_hi:[0,1]"
                    : "=v"(t1) : "v"(y1[m + q]), "v"(w[m + q]));
                asm("v_pk_fma_f32 %0, %1, %2, %3 op_sel:[1,1,0] op_sel_hi:[1,0,1] neg_lo:[0,1,0]"
                    : "=v"(y1[m + q]) : "v"(y1[m + q]), "v"(w[m + q]), "v"(t1));
                asm("v_pk_mul_f32 %0, %1, %2 op_sel:[0,0] op_sel_hi:[0,1]"
                    : "=v"(t2) : "v"(y2[m + q]), "v"(w[m + q]));
                asm("v_pk_fma_f32 %0, %1, %2, %3 op_sel:[1,1,0] op_sel_hi:[1,0,1] neg_lo:[0,1,0]"
                    : "=v"(y2[m + q]) : "v"(y2[m + q]), "v"(w[m + q]), "v"(t2));
            }
        }
        float acc1 = a1a[0] + a1b[0];
        float acc2 = a2a[0] + a2b[0];
        float tot1 = acc1 + __shfl_xor(acc1, 32, 64);
        float tot2 = acc2 + __shfl_xor(acc2, 32, 64);
        outp[(size_t)j * 128] = half ? tot2 : tot1;   // all 64 lanes store
    }
}

extern "C" void kernel_launch(void* const* d_in, const int* in_sizes, int n_in,
                              void* d_out, int out_size, void* d_ws, size_t ws_size,
                              hipStream_t stream) {
    // inputs: [0]=L (int scalar), [1]=log_dt (H,), [2]=C (H,32,2),
    //         [3]=log_A_real (H,32), [4]=A_imag (H,32)
    const float* log_dt     = (const float*)d_in[1];
    const float* Cv         = (const float*)d_in[2];
    const float* log_A_real = (const float*)d_in[3];
    const float* A_imag     = (const float*)d_in[4];
    float* Kout = (float*)d_out;

    const int Hn = in_sizes[1];          // 1024
    const int L  = out_size / Hn;        // 4096

    dim3 grid(Hn), block(256);
    hipLaunchKernelGGL(s4d_kernel, grid, block, 0, stream,
                       log_dt, Cv, log_A_real, A_imag, Kout, L);
}